// Round 1
// baseline (158.763 us; speedup 1.0000x reference)
//
#include <hip/hip_runtime.h>
#include <hip/hip_bf16.h>

// ROI bilinear crop+resize (tf.image.resize bilinear semantics, half-pixel
// centers, clip-before-floor), fused gather+interpolate.
// image: [H=128, W=128, C=512] f32; rois: [256 x (x,y,w,h)] i32; pool=14.
// Output: [256, pool, pool, C] f32.
//
// Layout: one 128-thread block per output pixel (roi, py, px). Each thread
// owns one float4 of the C=512 channels -> 4 coalesced 16B tap loads + one
// coalesced 16B store. Coordinate math is redundant per-thread but ~30 VALU
// ops, negligible vs the memory traffic.

__global__ __launch_bounds__(128)
void roi_bilinear_kernel(const float* __restrict__ img,
                         const int*   __restrict__ rois,
                         float*       __restrict__ out,
                         int W, int C, int pool) {
    const int pix = blockIdx.x;                 // roi*pool*pool + py*pool + px
    const int px  = pix % pool;
    const int tmp = pix / pool;
    const int py  = tmp % pool;
    const int roi = tmp / pool;

    const int4 rv = reinterpret_cast<const int4*>(rois)[roi]; // x, y, w, h
    const float poolf = (float)pool;

    // y axis: offset rv.y, size rv.w(h)
    const float hf = (float)rv.w;
    float sy = ((float)py + 0.5f) * (hf / poolf) - 0.5f;   // exact: true div like ref
    sy = fminf(fmaxf(sy, 0.0f), hf - 1.0f);                // clip BEFORE floor
    const int   i0y = (int)floorf(sy);
    const int   i1y = min(i0y + 1, rv.w - 1);
    const float fy  = sy - (float)i0y;
    const int   y0  = rv.y + i0y;
    const int   y1  = rv.y + i1y;

    // x axis: offset rv.x, size rv.z(w)
    const float wf = (float)rv.z;
    float sx = ((float)px + 0.5f) * (wf / poolf) - 0.5f;
    sx = fminf(fmaxf(sx, 0.0f), wf - 1.0f);
    const int   i0x = (int)floorf(sx);
    const int   i1x = min(i0x + 1, rv.z - 1);
    const float fx  = sx - (float)i0x;
    const int   x0  = rv.x + i0x;
    const int   x1  = rv.x + i1x;

    const int C4 = C >> 2;
    const int c4 = threadIdx.x;                 // float4 channel index, 0..C4-1

    const float4* imgv = reinterpret_cast<const float4*>(img);
    const size_t b00 = (size_t)(y0 * W + x0) * C4 + c4;
    const size_t b01 = (size_t)(y0 * W + x1) * C4 + c4;
    const size_t b10 = (size_t)(y1 * W + x0) * C4 + c4;
    const size_t b11 = (size_t)(y1 * W + x1) * C4 + c4;

    const float4 v00 = imgv[b00];
    const float4 v01 = imgv[b01];
    const float4 v10 = imgv[b10];
    const float4 v11 = imgv[b11];

    const float gx = 1.0f - fx;
    const float gy = 1.0f - fy;

    float4 o;
    o.x = (v00.x * gx + v01.x * fx) * gy + (v10.x * gx + v11.x * fx) * fy;
    o.y = (v00.y * gx + v01.y * fx) * gy + (v10.y * gx + v11.y * fx) * fy;
    o.z = (v00.z * gx + v01.z * fx) * gy + (v10.z * gx + v11.z * fx) * fy;
    o.w = (v00.w * gx + v01.w * fx) * gy + (v10.w * gx + v11.w * fx) * fy;

    reinterpret_cast<float4*>(out)[(size_t)pix * C4 + c4] = o;
}

extern "C" void kernel_launch(void* const* d_in, const int* in_sizes, int n_in,
                              void* d_out, int out_size, void* d_ws, size_t ws_size,
                              hipStream_t stream) {
    const float* img  = (const float*)d_in[0];   // [1,128,128,512] f32
    const int*   rois = (const int*)d_in[1];     // [1,256,4] i32
    // d_in[2] = pool_size scalar on device; derive pool on host from out_size.
    float* out = (float*)d_out;

    const int H = 128, W = 128, C = 512;
    (void)H;
    const int num_rois = in_sizes[1] / 4;        // 256

    // out_size = num_rois * pool^2 * C  ->  pool = isqrt(out_size/(num_rois*C))
    const int pp = out_size / (num_rois * C);    // pool^2
    int pool = 1;
    while ((pool + 1) * (pool + 1) <= pp) ++pool;

    const int npix = num_rois * pool * pool;     // 50176 blocks
    const int C4 = C / 4;                        // 128 threads
    roi_bilinear_kernel<<<npix, C4, 0, stream>>>(img, rois, out, W, C, pool);
}

// Round 3
// 156.220 us; speedup vs baseline: 1.0163x; 1.0163x over previous
//
#include <hip/hip_runtime.h>
#include <hip/hip_bf16.h>

// ROI bilinear crop+resize, round 2b: locality-restructured (compile fix:
// nontemporal store needs a native clang vector type, not HIP_vector_type).
//
// Block = one (roi, py) output row: 256 threads, 14 px x 512 ch.
//   - thread t: c4 = t & 127 (float4 channel), sub = t >> 7; px = sub, sub+2, ...
//   - all px in the block share the same two image rows (y0,y1) -> L1/L2 reuse
// XCD swizzle: blockIdx -> xcd = b&7 (round-robin dispatch), each XCD gets a
//   contiguous 1/8 of the (roi,py) space => per-XCD L2 working set ~ one ROI.
// Output stores are non-temporal (streaming, zero reuse) so they don't evict
//   the gather working set from L2.

typedef float vfloat4 __attribute__((ext_vector_type(4)));

__global__ __launch_bounds__(256)
void roi_bilinear_row_kernel(const float* __restrict__ img,
                             const int*   __restrict__ rois,
                             float*       __restrict__ out,
                             int W, int pool, int nroi) {
    const int C4 = 128;                    // 512 channels / 4 floats
    const int nblk = nroi * pool;

    // XCD-clustered remap (bijective when nblk % 8 == 0)
    int lin;
    if ((nblk & 7) == 0) {
        const int per_xcd = nblk >> 3;
        const int xcd = blockIdx.x & 7;
        const int j   = blockIdx.x >> 3;
        lin = xcd * per_xcd + j;
    } else {
        lin = blockIdx.x;
    }
    const int roi = lin / pool;
    const int py  = lin - roi * pool;

    const int4 rv = reinterpret_cast<const int4*>(rois)[roi]; // x, y, w, h
    const float poolf = (float)pool;

    // y axis (offset rv.y, size rv.w == h)
    const float hf = (float)rv.w;
    float sy = ((float)py + 0.5f) * (hf / poolf) - 0.5f;  // true div, like ref
    sy = fminf(fmaxf(sy, 0.0f), hf - 1.0f);               // clip BEFORE floor
    const int   i0y = (int)floorf(sy);
    const int   i1y = min(i0y + 1, rv.w - 1);
    const float fy  = sy - (float)i0y;
    const int   y0  = rv.y + i0y;
    const int   y1  = rv.y + i1y;
    const float gy  = 1.0f - fy;

    // x axis common factors (offset rv.x, size rv.z == w)
    const float wf = (float)rv.z;
    const float xscale = wf / poolf;
    const float xmax = wf - 1.0f;
    const int   xlim = rv.z - 1;

    const int c4  = threadIdx.x & (C4 - 1);
    const int sub = threadIdx.x >> 7;      // 0 or 1

    const vfloat4* __restrict__ imgv = reinterpret_cast<const vfloat4*>(img);
    vfloat4* __restrict__ outv = reinterpret_cast<vfloat4*>(out);

    const size_t row0 = (size_t)(y0 * W) * C4 + c4;
    const size_t row1 = (size_t)(y1 * W) * C4 + c4;
    const size_t outbase = (size_t)lin * pool * C4 + c4;

    for (int px = sub; px < pool; px += 2) {
        float sx = ((float)px + 0.5f) * xscale - 0.5f;
        sx = fminf(fmaxf(sx, 0.0f), xmax);
        const int   i0x = (int)floorf(sx);
        const int   i1x = min(i0x + 1, xlim);
        const float fx  = sx - (float)i0x;
        const int   x0  = (rv.x + i0x) * C4;
        const int   x1  = (rv.x + i1x) * C4;

        const vfloat4 v00 = imgv[row0 + x0];
        const vfloat4 v01 = imgv[row0 + x1];
        const vfloat4 v10 = imgv[row1 + x0];
        const vfloat4 v11 = imgv[row1 + x1];

        const float gx = 1.0f - fx;
        vfloat4 o = (v00 * gx + v01 * fx) * gy + (v10 * gx + v11 * fx) * fy;

        __builtin_nontemporal_store(o, &outv[outbase + (size_t)px * C4]);
    }
}

extern "C" void kernel_launch(void* const* d_in, const int* in_sizes, int n_in,
                              void* d_out, int out_size, void* d_ws, size_t ws_size,
                              hipStream_t stream) {
    const float* img  = (const float*)d_in[0];   // [1,128,128,512] f32
    const int*   rois = (const int*)d_in[1];     // [1,256,4] i32
    float* out = (float*)d_out;

    const int W = 128, C = 512;
    const int num_rois = in_sizes[1] / 4;        // 256

    // out_size = num_rois * pool^2 * C  ->  pool = isqrt(out_size/(num_rois*C))
    const int pp = out_size / (num_rois * C);    // pool^2
    int pool = 1;
    while ((pool + 1) * (pool + 1) <= pp) ++pool;

    const int nblk = num_rois * pool;            // 3584 blocks (256 thr each)
    roi_bilinear_row_kernel<<<nblk, 256, 0, stream>>>(img, rois, out,
                                                      W, pool, num_rois);
}